// Round 7
// baseline (1523.622 us; speedup 1.0000x reference)
//
#include <hip/hip_runtime.h>

// GRU encoder: B=64, T=512, F=64, H=256, D=64.
//   k1: xproj = x @ kernel + bias -> f16 in d_ws (dot2 GEMM, unchanged).
//   k2: MFMA scan. 4 blocks x 16 batches (M=16), 512 threads = 8 waves.
//       rec(16x768) = h(16x256) @ W_rec(256x768) via mfma_f32_16x16x32_f16.
//       Wave w owns n-tiles {w,w+8,..,w+40}: full K per tile -> no partials;
//       z/r/h tiles for the same (batch,col) land in the SAME lane -> gates
//       are register-only. B-frags (192 regs) live in VGPR/AGPR (MFMA reads
//       AGPR operands natively -> no accvgpr-move tax). h_new goes back to a
//       double-buffered A-layout LDS buffer; ONE barrier per step.
//       Rationale: R2/R4 showed the dot2 scan is LDS-BW-bound on the h
//       broadcast (128 KB/step/CU); MFMA shares A internally -> 8 KB/step
//       per 16 batches per wave.

typedef _Float16 half2_t __attribute__((ext_vector_type(2)));
typedef _Float16 f16x4_t __attribute__((ext_vector_type(4)));
typedef _Float16 f16x8_t __attribute__((ext_vector_type(8)));
typedef float f32x4_t __attribute__((ext_vector_type(4)));

#define LOG2E 1.4426950408889634f

__device__ __forceinline__ float fast_sigmoid(float x) {
  float e = __builtin_amdgcn_exp2f(-x * LOG2E);
  return __builtin_amdgcn_rcpf(1.0f + e);
}
__device__ __forceinline__ float fast_tanh(float x) {
  float e = __builtin_amdgcn_exp2f(x * (2.0f * LOG2E));
  return 1.0f - 2.0f * __builtin_amdgcn_rcpf(1.0f + e);
}

// ---------------------------------------------------------------------------
// Kernel 1: xproj GEMM.  C(32768x768) = A(32768x64) @ B(64x768) + bias.
// ---------------------------------------------------------------------------
__global__ __launch_bounds__(256, 4) void xproj_gemm(
    const float* __restrict__ x, const float* __restrict__ kmat,
    const float* __restrict__ bias, _Float16* __restrict__ xp) {
  __shared__ half2_t As2[32][132];  // [kpair][row]
  __shared__ half2_t Bs2[32][132];  // [kpair][col]
  const int tid = threadIdx.x;
  const int rb = blockIdx.x * 128;
  const int cb = blockIdx.y * 128;

  {
    const int k4 = (tid & 15) * 4;
    const int r0 = tid >> 4;
#pragma unroll
    for (int p = 0; p < 8; ++p) {
      int r = r0 + p * 16;
      float4 v = *(const float4*)(x + (size_t)(rb + r) * 64 + k4);
      half2_t lo, hi;
      lo[0] = (_Float16)v.x; lo[1] = (_Float16)v.y;
      hi[0] = (_Float16)v.z; hi[1] = (_Float16)v.w;
      As2[k4 / 2][r] = lo;
      As2[k4 / 2 + 1][r] = hi;
    }
  }
  {
    const int c4 = (tid & 31) * 4;
    const int kp0 = tid >> 5;
#pragma unroll
    for (int p = 0; p < 4; ++p) {
      int kp = kp0 + p * 8;
      float4 va = *(const float4*)(kmat + (size_t)(2 * kp) * 768 + cb + c4);
      float4 vb = *(const float4*)(kmat + (size_t)(2 * kp + 1) * 768 + cb + c4);
      half2_t o0, o1, o2, o3;
      o0[0] = (_Float16)va.x; o0[1] = (_Float16)vb.x;
      o1[0] = (_Float16)va.y; o1[1] = (_Float16)vb.y;
      o2[0] = (_Float16)va.z; o2[1] = (_Float16)vb.z;
      o3[0] = (_Float16)va.w; o3[1] = (_Float16)vb.w;
      Bs2[kp][c4 + 0] = o0;
      Bs2[kp][c4 + 1] = o1;
      Bs2[kp][c4 + 2] = o2;
      Bs2[kp][c4 + 3] = o3;
    }
  }
  __syncthreads();

  const int tx = tid & 15, ty = tid >> 4;
  const int r0 = ty * 8;
  const int c0 = tx * 4;
  float acc[8][8];
  {
    float4 b0 = *(const float4*)(bias + cb + c0);
    float4 b1 = *(const float4*)(bias + cb + 64 + c0);
    float bz[8] = {b0.x, b0.y, b0.z, b0.w, b1.x, b1.y, b1.z, b1.w};
#pragma unroll
    for (int i = 0; i < 8; ++i)
#pragma unroll
      for (int j = 0; j < 8; ++j) acc[i][j] = bz[j];
  }

#pragma unroll 2
  for (int kp = 0; kp < 32; ++kp) {
    half2_t a2[8], b2[8];
    *(int4*)(&a2[0]) = *(const int4*)(&As2[kp][r0]);
    *(int4*)(&a2[4]) = *(const int4*)(&As2[kp][r0 + 4]);
    *(int2*)(&b2[0]) = *(const int2*)(&Bs2[kp][c0]);
    *(int2*)(&b2[2]) = *(const int2*)(&Bs2[kp][c0 + 2]);
    *(int2*)(&b2[4]) = *(const int2*)(&Bs2[kp][64 + c0]);
    *(int2*)(&b2[6]) = *(const int2*)(&Bs2[kp][64 + c0 + 2]);
#pragma unroll
    for (int i = 0; i < 8; ++i)
#pragma unroll
      for (int j = 0; j < 8; ++j)
        acc[i][j] = __builtin_amdgcn_fdot2(a2[i], b2[j], acc[i][j], false);
  }

#pragma unroll
  for (int i = 0; i < 8; ++i) {
    f16x4_t o0, o1;
#pragma unroll
    for (int j = 0; j < 4; ++j) {
      o0[j] = (_Float16)acc[i][j];
      o1[j] = (_Float16)acc[i][4 + j];
    }
    _Float16* dst = xp + (size_t)(rb + r0 + i) * 768 + cb;
    *(f16x4_t*)(dst + c0) = o0;
    *(f16x4_t*)(dst + 64 + c0) = o1;
  }
}

// ---------------------------------------------------------------------------
// Kernel 2: MFMA GRU scan. 4 blocks, each owns batches blk*16..blk*16+15.
// Layouts (mfma_f32_16x16x32_f16, per cdna4 guide / m89 / m120):
//   A-frag : lane holds A[m = lane&15][k = (lane>>4)*8 + j], j=0..7
//   B-frag : lane holds B[k = (lane>>4)*8 + j][n = lane&15]
//   C/D    : lane reg r holds D[row = (lane>>4)*4 + r][col = lane&15]
// ---------------------------------------------------------------------------
__global__ __launch_bounds__(512, 1) void gru_scan_mfma(
    const _Float16* __restrict__ xp, const float* __restrict__ wr,
    const float* __restrict__ dw, const float* __restrict__ db,
    float* __restrict__ out, float* __restrict__ state) {
  __shared__ _Float16 hA[2][16][264];  // A-layout h, double-buffered, padded
  __shared__ float hf[16][256];        // h_last (f32) for the dense head

  const int tid = threadIdx.x;
  const int blk = blockIdx.x;  // 0..3
  const int w = tid >> 6;      // wave 0..7
  const int l = tid & 63;
  const int q = l >> 4;   // quad 0..3
  const int nl = l & 15;  // lane&15

  // --- B fragments: wave w covers n-tiles {w+8i}, i=0..5 (z,z,r,r,h,h).
  f16x8_t wfrag[6][8];
#pragma unroll
  for (int i = 0; i < 6; ++i) {
    const int nt = w + 8 * i;
#pragma unroll
    for (int kt = 0; kt < 8; ++kt) {
      f16x8_t f;
#pragma unroll
      for (int j = 0; j < 8; ++j)
        f[j] = (_Float16)wr[(size_t)(kt * 32 + q * 8 + j) * 768 + nt * 16 + nl];
      wfrag[i][kt] = f;
    }
  }

  // zero both h buffers
  for (int i = tid; i < 2 * 16 * 264; i += 512) (&hA[0][0][0])[i] = (_Float16)0;
  __syncthreads();

  float hold[2][4] = {{0.f, 0.f, 0.f, 0.f}, {0.f, 0.f, 0.f, 0.f}};

  for (int t = 0; t < 512; ++t) {
    const int cur = t & 1;

    // x gate inputs for this step (issued early; consumed after MFMA phase)
    _Float16 xzv[2][4], xrv[2][4], xhv[2][4];
#pragma unroll
    for (int tr = 0; tr < 2; ++tr) {
      const int col = (w + 8 * tr) * 16 + nl;
#pragma unroll
      for (int r = 0; r < 4; ++r) {
        const int bm = blk * 16 + q * 4 + r;
        const _Float16* xrow = xp + ((size_t)bm * 512 + t) * 768;
        xzv[tr][r] = xrow[col];
        xrv[tr][r] = xrow[col + 256];
        xhv[tr][r] = xrow[col + 512];
      }
    }

    // --- rec = h @ W_rec for this wave's 6 n-tiles, full K
    f32x4_t acc[6];
#pragma unroll
    for (int i = 0; i < 6; ++i) acc[i] = (f32x4_t){0.f, 0.f, 0.f, 0.f};
#pragma unroll
    for (int kt = 0; kt < 8; ++kt) {
      f16x8_t afrag = *(const f16x8_t*)&hA[cur][nl][kt * 32 + q * 8];
#pragma unroll
      for (int i = 0; i < 6; ++i)
        acc[i] = __builtin_amdgcn_mfma_f32_16x16x32_f16(afrag, wfrag[i][kt],
                                                        acc[i], 0, 0, 0);
    }

    // --- gates, entirely in-lane (z: acc[tr], r: acc[2+tr], h: acc[4+tr])
#pragma unroll
    for (int tr = 0; tr < 2; ++tr) {
      const int col = (w + 8 * tr) * 16 + nl;
#pragma unroll
      for (int r = 0; r < 4; ++r) {
        const int m = q * 4 + r;
        float z = fast_sigmoid((float)xzv[tr][r] + acc[tr][r]);
        float rg = fast_sigmoid((float)xrv[tr][r] + acc[2 + tr][r]);
        float hc = fast_tanh((float)xhv[tr][r] + rg * acc[4 + tr][r]);
        float hn = z * hold[tr][r] + (1.0f - z) * hc;
        hold[tr][r] = hn;
        out[((size_t)(blk * 16 + m) * 512 + t) * 256 + col] = hn;
        hA[1 - cur][m][col] = (_Float16)hn;
      }
    }
    __syncthreads();
  }

  // --- dense head: state = tanh(h_last @ dense_w + dense_b)
#pragma unroll
  for (int tr = 0; tr < 2; ++tr)
#pragma unroll
    for (int r = 0; r < 4; ++r)
      hf[q * 4 + r][(w + 8 * tr) * 16 + nl] = hold[tr][r];
  __syncthreads();

  for (int o = tid; o < 16 * 64; o += 512) {
    const int m = o >> 6, d = o & 63;
    float acc = db[d];
#pragma unroll 8
    for (int k = 0; k < 256; ++k) acc = fmaf(hf[m][k], dw[k * 64 + d], acc);
    state[(size_t)(blk * 16 + m) * 64 + d] = fast_tanh(acc);
  }
}

// ---------------------------------------------------------------------------
extern "C" void kernel_launch(void* const* d_in, const int* in_sizes, int n_in,
                              void* d_out, int out_size, void* d_ws,
                              size_t ws_size, hipStream_t stream) {
  const float* x = (const float*)d_in[0];     // (64,512,64)
  const float* kmat = (const float*)d_in[1];  // (64,768)
  const float* wr = (const float*)d_in[2];    // (256,768)
  const float* bias = (const float*)d_in[3];  // (768,)
  const float* dw = (const float*)d_in[4];    // (256,64)
  const float* db = (const float*)d_in[5];    // (64,)

  float* out = (float*)d_out;                   // (64,512,256)
  float* state = out + (size_t)64 * 512 * 256;  // (64,64)
  _Float16* xp = (_Float16*)d_ws;               // 64*512*768 f16 = 48 MiB

  dim3 gg(32768 / 128, 768 / 128);
  xproj_gemm<<<gg, 256, 0, stream>>>(x, kmat, bias, xp);
  gru_scan_mfma<<<4, 512, 0, stream>>>(xp, wr, dw, db, out, state);
}

// Round 8
// 697.200 us; speedup vs baseline: 2.1853x; 2.1853x over previous
//
#include <hip/hip_runtime.h>

// GRU encoder: B=64, T=512, F=64, H=256, D=64.
//   k1: xproj = x @ kernel + bias -> f16 in d_ws (dot2 GEMM, unchanged).
//   k2: MFMA scan, 64 blocks x 1 batch x 512 threads (8 waves).
//       rec(768) = h(256) @ W_rec(256x768) via mfma_f32_16x16x32_f16 where
//       ALL 16 A-rows carry the same h vector: afrag is a quad-broadcast
//       LDS read (conflict-free, 512B buffer), and every lane's acc[i][0]
//       holds rec for its column -> gates fully in-lane, q==0 lanes store.
//       Regs: 192 wfrag + 24 acc + ~25 live = ~240 < 256-cap at 8 waves/CU
//       (R7's 4-block variant spilled: ~270 regs -> scratch, 6800 cyc/step).

typedef _Float16 half2_t __attribute__((ext_vector_type(2)));
typedef _Float16 f16x4_t __attribute__((ext_vector_type(4)));
typedef _Float16 f16x8_t __attribute__((ext_vector_type(8)));
typedef float f32x4_t __attribute__((ext_vector_type(4)));

#define LOG2E 1.4426950408889634f

__device__ __forceinline__ float fast_sigmoid(float x) {
  float e = __builtin_amdgcn_exp2f(-x * LOG2E);
  return __builtin_amdgcn_rcpf(1.0f + e);
}
__device__ __forceinline__ float fast_tanh(float x) {
  float e = __builtin_amdgcn_exp2f(x * (2.0f * LOG2E));
  return 1.0f - 2.0f * __builtin_amdgcn_rcpf(1.0f + e);
}

// ---------------------------------------------------------------------------
// Kernel 1: xproj GEMM.  C(32768x768) = A(32768x64) @ B(64x768) + bias.
// ---------------------------------------------------------------------------
__global__ __launch_bounds__(256, 4) void xproj_gemm(
    const float* __restrict__ x, const float* __restrict__ kmat,
    const float* __restrict__ bias, _Float16* __restrict__ xp) {
  __shared__ half2_t As2[32][132];  // [kpair][row]
  __shared__ half2_t Bs2[32][132];  // [kpair][col]
  const int tid = threadIdx.x;
  const int rb = blockIdx.x * 128;
  const int cb = blockIdx.y * 128;

  {
    const int k4 = (tid & 15) * 4;
    const int r0 = tid >> 4;
#pragma unroll
    for (int p = 0; p < 8; ++p) {
      int r = r0 + p * 16;
      float4 v = *(const float4*)(x + (size_t)(rb + r) * 64 + k4);
      half2_t lo, hi;
      lo[0] = (_Float16)v.x; lo[1] = (_Float16)v.y;
      hi[0] = (_Float16)v.z; hi[1] = (_Float16)v.w;
      As2[k4 / 2][r] = lo;
      As2[k4 / 2 + 1][r] = hi;
    }
  }
  {
    const int c4 = (tid & 31) * 4;
    const int kp0 = tid >> 5;
#pragma unroll
    for (int p = 0; p < 4; ++p) {
      int kp = kp0 + p * 8;
      float4 va = *(const float4*)(kmat + (size_t)(2 * kp) * 768 + cb + c4);
      float4 vb = *(const float4*)(kmat + (size_t)(2 * kp + 1) * 768 + cb + c4);
      half2_t o0, o1, o2, o3;
      o0[0] = (_Float16)va.x; o0[1] = (_Float16)vb.x;
      o1[0] = (_Float16)va.y; o1[1] = (_Float16)vb.y;
      o2[0] = (_Float16)va.z; o2[1] = (_Float16)vb.z;
      o3[0] = (_Float16)va.w; o3[1] = (_Float16)vb.w;
      Bs2[kp][c4 + 0] = o0;
      Bs2[kp][c4 + 1] = o1;
      Bs2[kp][c4 + 2] = o2;
      Bs2[kp][c4 + 3] = o3;
    }
  }
  __syncthreads();

  const int tx = tid & 15, ty = tid >> 4;
  const int r0 = ty * 8;
  const int c0 = tx * 4;
  float acc[8][8];
  {
    float4 b0 = *(const float4*)(bias + cb + c0);
    float4 b1 = *(const float4*)(bias + cb + 64 + c0);
    float bz[8] = {b0.x, b0.y, b0.z, b0.w, b1.x, b1.y, b1.z, b1.w};
#pragma unroll
    for (int i = 0; i < 8; ++i)
#pragma unroll
      for (int j = 0; j < 8; ++j) acc[i][j] = bz[j];
  }

#pragma unroll 2
  for (int kp = 0; kp < 32; ++kp) {
    half2_t a2[8], b2[8];
    *(int4*)(&a2[0]) = *(const int4*)(&As2[kp][r0]);
    *(int4*)(&a2[4]) = *(const int4*)(&As2[kp][r0 + 4]);
    *(int2*)(&b2[0]) = *(const int2*)(&Bs2[kp][c0]);
    *(int2*)(&b2[2]) = *(const int2*)(&Bs2[kp][c0 + 2]);
    *(int2*)(&b2[4]) = *(const int2*)(&Bs2[kp][64 + c0]);
    *(int2*)(&b2[6]) = *(const int2*)(&Bs2[kp][64 + c0 + 2]);
#pragma unroll
    for (int i = 0; i < 8; ++i)
#pragma unroll
      for (int j = 0; j < 8; ++j)
        acc[i][j] = __builtin_amdgcn_fdot2(a2[i], b2[j], acc[i][j], false);
  }

#pragma unroll
  for (int i = 0; i < 8; ++i) {
    f16x4_t o0, o1;
#pragma unroll
    for (int j = 0; j < 4; ++j) {
      o0[j] = (_Float16)acc[i][j];
      o1[j] = (_Float16)acc[i][4 + j];
    }
    _Float16* dst = xp + (size_t)(rb + r0 + i) * 768 + cb;
    *(f16x4_t*)(dst + c0) = o0;
    *(f16x4_t*)(dst + 64 + c0) = o1;
  }
}

// ---------------------------------------------------------------------------
// Kernel 2: MFMA GRU scan. 64 blocks, block b = batch b. 512 thr = 8 waves.
// Wave w owns n-tiles {w+8i, i=0..5}; for col group g in {w, w+8}:
//   z = acc[tr], r = acc[2+tr], h = acc[4+tr] (tr = g>>3 selector), all
//   in-lane. A-rows all carry h => every lane's acc[i][0] is the full rec.
// ---------------------------------------------------------------------------
__global__ __launch_bounds__(512, 2) void gru_scan_mfma(
    const _Float16* __restrict__ xp, const float* __restrict__ wr,
    const float* __restrict__ dw, const float* __restrict__ db,
    float* __restrict__ out, float* __restrict__ state) {
  __shared__ alignas(16) _Float16 hA[2][256];  // h, double-buffered (1 KiB)

  const int tid = threadIdx.x;
  const int b = blockIdx.x;  // batch
  const int w = tid >> 6;    // wave 0..7
  const int l = tid & 63;
  const int q = l >> 4;   // quad 0..3
  const int nl = l & 15;  // lane&15

  // --- B fragments: wave w covers n-tiles {w+8i} (z,z,r,r,h,h), 192 VGPRs
  f16x8_t wfrag[6][8];
#pragma unroll
  for (int i = 0; i < 6; ++i) {
    const int nt = w + 8 * i;
#pragma unroll
    for (int kt = 0; kt < 8; ++kt) {
      f16x8_t f;
#pragma unroll
      for (int j = 0; j < 8; ++j)
        f[j] = (_Float16)wr[(size_t)(kt * 32 + q * 8 + j) * 768 + nt * 16 + nl];
      wfrag[i][kt] = f;
    }
  }

  if (tid < 256) {
    hA[0][tid] = (_Float16)0.0f;
    hA[1][tid] = (_Float16)0.0f;
  }
  __syncthreads();

  const _Float16* xpb = xp + (size_t)b * 512 * 768;
  float* outb = out + (size_t)b * 512 * 256;
  const int col0 = w * 16 + nl;   // col group w     (tr=0)
  const int col1 = col0 + 128;    // col group w + 8 (tr=1)
  float hold0 = 0.0f, hold1 = 0.0f;  // h_prev for col0/col1 (all lanes)

  for (int t = 0; t < 512; ++t) {
    const int cur = t & 1;

    // x gate inputs (coalesced 16-lane segments; same across quads)
    const _Float16* xrow = xpb + (size_t)t * 768;
    _Float16 xz0 = xrow[col0], xr0 = xrow[col0 + 256], xh0 = xrow[col0 + 512];
    _Float16 xz1 = xrow[col1], xr1 = xrow[col1 + 256], xh1 = xrow[col1 + 512];

    // --- rec = h @ W_rec; afrag = same 16B of h for all lanes in a quad
    // (LDS broadcast). All A-rows equal h => all D-rows equal rec.
    f32x4_t acc[6];
#pragma unroll
    for (int i = 0; i < 6; ++i) acc[i] = (f32x4_t){0.f, 0.f, 0.f, 0.f};
#pragma unroll
    for (int kt = 0; kt < 8; ++kt) {
      f16x8_t afrag = *(const f16x8_t*)&hA[cur][kt * 32 + q * 8];
#pragma unroll
      for (int i = 0; i < 6; ++i)
        acc[i] = __builtin_amdgcn_mfma_f32_16x16x32_f16(afrag, wfrag[i][kt],
                                                        acc[i], 0, 0, 0);
    }

    // --- gates: all lanes compute (quads redundant), q==0 stores
    float z0 = fast_sigmoid((float)xz0 + acc[0][0]);
    float r0 = fast_sigmoid((float)xr0 + acc[2][0]);
    float hc0 = fast_tanh((float)xh0 + r0 * acc[4][0]);
    float hn0 = z0 * hold0 + (1.0f - z0) * hc0;
    hold0 = hn0;

    float z1 = fast_sigmoid((float)xz1 + acc[1][0]);
    float r1 = fast_sigmoid((float)xr1 + acc[3][0]);
    float hc1 = fast_tanh((float)xh1 + r1 * acc[5][0]);
    float hn1 = z1 * hold1 + (1.0f - z1) * hc1;
    hold1 = hn1;

    if (q == 0) {
      outb[(size_t)t * 256 + col0] = hn0;
      outb[(size_t)t * 256 + col1] = hn1;
      hA[1 - cur][col0] = (_Float16)hn0;
      hA[1 - cur][col1] = (_Float16)hn1;
    }
    __syncthreads();
  }

  // --- dense head: state = tanh(h_last @ dense_w + dense_b); h_last in hA[0]
  if (tid < 64) {
    float acc = db[tid];
#pragma unroll 8
    for (int k = 0; k < 256; ++k)
      acc = fmaf((float)hA[0][k], dw[k * 64 + tid], acc);
    state[(size_t)b * 64 + tid] = fast_tanh(acc);
  }
}

// ---------------------------------------------------------------------------
extern "C" void kernel_launch(void* const* d_in, const int* in_sizes, int n_in,
                              void* d_out, int out_size, void* d_ws,
                              size_t ws_size, hipStream_t stream) {
  const float* x = (const float*)d_in[0];     // (64,512,64)
  const float* kmat = (const float*)d_in[1];  // (64,768)
  const float* wr = (const float*)d_in[2];    // (256,768)
  const float* bias = (const float*)d_in[3];  // (768,)
  const float* dw = (const float*)d_in[4];    // (256,64)
  const float* db = (const float*)d_in[5];    // (64,)

  float* out = (float*)d_out;                   // (64,512,256)
  float* state = out + (size_t)64 * 512 * 256;  // (64,64)
  _Float16* xp = (_Float16*)d_ws;               // 64*512*768 f16 = 48 MiB

  dim3 gg(32768 / 128, 768 / 128);
  xproj_gemm<<<gg, 256, 0, stream>>>(x, kmat, bias, xp);
  gru_scan_mfma<<<64, 512, 0, stream>>>(xp, wr, dw, db, out, state);
}

// Round 9
// 665.549 us; speedup vs baseline: 2.2893x; 1.0476x over previous
//
#include <hip/hip_runtime.h>

// GRU encoder: B=64, T=512, F=64, H=256, D=64.
//   k1: xproj = x @ kernel + bias -> f16 in d_ws (dot2 GEMM, unchanged).
//   k2: MFMA scan, 64 blocks x 1 batch x 512 threads (8 waves).
//       R8 result: all structures converge ~2880 cyc/step => bottleneck is
//       the __syncthreads vmcnt(0) drain (out-stores + x-loads serialized
//       into every step) + x HBM latency, NOT compute.
//       This round: CK-style barrier (s_waitcnt lgkmcnt(0); s_barrier) so
//       global loads/stores stay in flight across steps, + 2-step register
//       prefetch of x. h exchange via LDS is the only barrier-drained dep.

typedef _Float16 half2_t __attribute__((ext_vector_type(2)));
typedef _Float16 f16x4_t __attribute__((ext_vector_type(4)));
typedef _Float16 f16x8_t __attribute__((ext_vector_type(8)));
typedef float f32x4_t __attribute__((ext_vector_type(4)));

#define LOG2E 1.4426950408889634f

__device__ __forceinline__ float fast_sigmoid(float x) {
  float e = __builtin_amdgcn_exp2f(-x * LOG2E);
  return __builtin_amdgcn_rcpf(1.0f + e);
}
__device__ __forceinline__ float fast_tanh(float x) {
  float e = __builtin_amdgcn_exp2f(x * (2.0f * LOG2E));
  return 1.0f - 2.0f * __builtin_amdgcn_rcpf(1.0f + e);
}

// LDS-only barrier: does NOT drain vmcnt, so global x-loads/out-stores
// pipeline across steps (composable_kernel block_sync_lds pattern).
__device__ __forceinline__ void sync_lds() {
  asm volatile("s_waitcnt lgkmcnt(0)\n\ts_barrier" ::: "memory");
}

// ---------------------------------------------------------------------------
// Kernel 1: xproj GEMM.  C(32768x768) = A(32768x64) @ B(64x768) + bias.
// ---------------------------------------------------------------------------
__global__ __launch_bounds__(256, 4) void xproj_gemm(
    const float* __restrict__ x, const float* __restrict__ kmat,
    const float* __restrict__ bias, _Float16* __restrict__ xp) {
  __shared__ half2_t As2[32][132];  // [kpair][row]
  __shared__ half2_t Bs2[32][132];  // [kpair][col]
  const int tid = threadIdx.x;
  const int rb = blockIdx.x * 128;
  const int cb = blockIdx.y * 128;

  {
    const int k4 = (tid & 15) * 4;
    const int r0 = tid >> 4;
#pragma unroll
    for (int p = 0; p < 8; ++p) {
      int r = r0 + p * 16;
      float4 v = *(const float4*)(x + (size_t)(rb + r) * 64 + k4);
      half2_t lo, hi;
      lo[0] = (_Float16)v.x; lo[1] = (_Float16)v.y;
      hi[0] = (_Float16)v.z; hi[1] = (_Float16)v.w;
      As2[k4 / 2][r] = lo;
      As2[k4 / 2 + 1][r] = hi;
    }
  }
  {
    const int c4 = (tid & 31) * 4;
    const int kp0 = tid >> 5;
#pragma unroll
    for (int p = 0; p < 4; ++p) {
      int kp = kp0 + p * 8;
      float4 va = *(const float4*)(kmat + (size_t)(2 * kp) * 768 + cb + c4);
      float4 vb = *(const float4*)(kmat + (size_t)(2 * kp + 1) * 768 + cb + c4);
      half2_t o0, o1, o2, o3;
      o0[0] = (_Float16)va.x; o0[1] = (_Float16)vb.x;
      o1[0] = (_Float16)va.y; o1[1] = (_Float16)vb.y;
      o2[0] = (_Float16)va.z; o2[1] = (_Float16)vb.z;
      o3[0] = (_Float16)va.w; o3[1] = (_Float16)vb.w;
      Bs2[kp][c4 + 0] = o0;
      Bs2[kp][c4 + 1] = o1;
      Bs2[kp][c4 + 2] = o2;
      Bs2[kp][c4 + 3] = o3;
    }
  }
  __syncthreads();

  const int tx = tid & 15, ty = tid >> 4;
  const int r0 = ty * 8;
  const int c0 = tx * 4;
  float acc[8][8];
  {
    float4 b0 = *(const float4*)(bias + cb + c0);
    float4 b1 = *(const float4*)(bias + cb + 64 + c0);
    float bz[8] = {b0.x, b0.y, b0.z, b0.w, b1.x, b1.y, b1.z, b1.w};
#pragma unroll
    for (int i = 0; i < 8; ++i)
#pragma unroll
      for (int j = 0; j < 8; ++j) acc[i][j] = bz[j];
  }

#pragma unroll 2
  for (int kp = 0; kp < 32; ++kp) {
    half2_t a2[8], b2[8];
    *(int4*)(&a2[0]) = *(const int4*)(&As2[kp][r0]);
    *(int4*)(&a2[4]) = *(const int4*)(&As2[kp][r0 + 4]);
    *(int2*)(&b2[0]) = *(const int2*)(&Bs2[kp][c0]);
    *(int2*)(&b2[2]) = *(const int2*)(&Bs2[kp][c0 + 2]);
    *(int2*)(&b2[4]) = *(const int2*)(&Bs2[kp][64 + c0]);
    *(int2*)(&b2[6]) = *(const int2*)(&Bs2[kp][64 + c0 + 2]);
#pragma unroll
    for (int i = 0; i < 8; ++i)
#pragma unroll
      for (int j = 0; j < 8; ++j)
        acc[i][j] = __builtin_amdgcn_fdot2(a2[i], b2[j], acc[i][j], false);
  }

#pragma unroll
  for (int i = 0; i < 8; ++i) {
    f16x4_t o0, o1;
#pragma unroll
    for (int j = 0; j < 4; ++j) {
      o0[j] = (_Float16)acc[i][j];
      o1[j] = (_Float16)acc[i][4 + j];
    }
    _Float16* dst = xp + (size_t)(rb + r0 + i) * 768 + cb;
    *(f16x4_t*)(dst + c0) = o0;
    *(f16x4_t*)(dst + 64 + c0) = o1;
  }
}

// ---------------------------------------------------------------------------
// Kernel 2: MFMA GRU scan. 64 blocks, block b = batch b. 512 thr = 8 waves.
// Wave w owns n-tiles {w+8i, i=0..5} (z,z,r,r,h,h); A-rows all carry h so
// every lane's acc[i][0] is rec for its column; gates in-lane, q==0 stores.
// ---------------------------------------------------------------------------
__global__ __launch_bounds__(512, 2) void gru_scan_mfma(
    const _Float16* __restrict__ xp, const float* __restrict__ wr,
    const float* __restrict__ dw, const float* __restrict__ db,
    float* __restrict__ out, float* __restrict__ state) {
  __shared__ alignas(16) _Float16 hA[2][256];  // h, double-buffered (1 KiB)

  const int tid = threadIdx.x;
  const int b = blockIdx.x;  // batch
  const int w = tid >> 6;    // wave 0..7
  const int l = tid & 63;
  const int q = l >> 4;   // quad 0..3
  const int nl = l & 15;  // lane&15

  // --- B fragments: wave w covers n-tiles {w+8i} (z,z,r,r,h,h), 192 regs
  f16x8_t wfrag[6][8];
#pragma unroll
  for (int i = 0; i < 6; ++i) {
    const int nt = w + 8 * i;
#pragma unroll
    for (int kt = 0; kt < 8; ++kt) {
      f16x8_t f;
#pragma unroll
      for (int j = 0; j < 8; ++j)
        f[j] = (_Float16)wr[(size_t)(kt * 32 + q * 8 + j) * 768 + nt * 16 + nl];
      wfrag[i][kt] = f;
    }
  }

  if (tid < 256) {
    hA[0][tid] = (_Float16)0.0f;
    hA[1][tid] = (_Float16)0.0f;
  }
  __syncthreads();

  const _Float16* xpb = xp + (size_t)b * 512 * 768;
  float* outb = out + (size_t)b * 512 * 256;
  const int col0 = w * 16 + nl;      // col group w     (tr=0)
  const int col1 = col0 + 128;       // col group w + 8 (tr=1)
  float hold0 = 0.0f, hold1 = 0.0f;  // h_prev for col0/col1

  // 2-step x prefetch buffers (registers)
  _Float16 xva[6], xvb[6];
  {
    const _Float16* x0 = xpb;        // t = 0
    const _Float16* x1 = xpb + 768;  // t = 1
    xva[0] = x0[col0]; xva[1] = x0[col0 + 256]; xva[2] = x0[col0 + 512];
    xva[3] = x0[col1]; xva[4] = x0[col1 + 256]; xva[5] = x0[col1 + 512];
    xvb[0] = x1[col0]; xvb[1] = x1[col0 + 256]; xvb[2] = x1[col0 + 512];
    xvb[3] = x1[col1]; xvb[4] = x1[col1 + 256]; xvb[5] = x1[col1 + 512];
  }

  auto step = [&](int t, _Float16* xv) {
    const int cur = t & 1;

    // --- rec = h @ W_rec; afrag = quad-broadcast 16B of h (conflict-free)
    f32x4_t acc[6];
#pragma unroll
    for (int i = 0; i < 6; ++i) acc[i] = (f32x4_t){0.f, 0.f, 0.f, 0.f};
#pragma unroll
    for (int kt = 0; kt < 8; ++kt) {
      f16x8_t afrag = *(const f16x8_t*)&hA[cur][kt * 32 + q * 8];
#pragma unroll
      for (int i = 0; i < 6; ++i)
        acc[i] = __builtin_amdgcn_mfma_f32_16x16x32_f16(afrag, wfrag[i][kt],
                                                        acc[i], 0, 0, 0);
    }

    // --- gates (all quads redundant; q==0 stores)
    float z0 = fast_sigmoid((float)xv[0] + acc[0][0]);
    float r0 = fast_sigmoid((float)xv[1] + acc[2][0]);
    float hc0 = fast_tanh((float)xv[2] + r0 * acc[4][0]);
    float hn0 = z0 * hold0 + (1.0f - z0) * hc0;
    hold0 = hn0;

    float z1 = fast_sigmoid((float)xv[3] + acc[1][0]);
    float r1 = fast_sigmoid((float)xv[4] + acc[3][0]);
    float hc1 = fast_tanh((float)xv[5] + r1 * acc[5][0]);
    float hn1 = z1 * hold1 + (1.0f - z1) * hc1;
    hold1 = hn1;

    if (q == 0) {
      outb[(size_t)t * 256 + col0] = hn0;   // fire-and-forget (no vmcnt drain)
      outb[(size_t)t * 256 + col1] = hn1;
      hA[1 - cur][col0] = (_Float16)hn0;
      hA[1 - cur][col1] = (_Float16)hn1;
    }

    // --- prefetch x for t+2 into the buffer just consumed
    int tp = t + 2 <= 511 ? t + 2 : 511;
    const _Float16* xn = xpb + (size_t)tp * 768;
    xv[0] = xn[col0]; xv[1] = xn[col0 + 256]; xv[2] = xn[col0 + 512];
    xv[3] = xn[col1]; xv[4] = xn[col1 + 256]; xv[5] = xn[col1 + 512];

    sync_lds();  // LDS-only barrier: global ops stay in flight
  };

  for (int tt = 0; tt < 256; ++tt) {
    step(2 * tt, xva);
    step(2 * tt + 1, xvb);
  }

  // --- dense head: state = tanh(h_last @ dense_w + dense_b); h_last in hA[0]
  if (tid < 64) {
    float acc = db[tid];
#pragma unroll 8
    for (int k = 0; k < 256; ++k)
      acc = fmaf((float)hA[0][k], dw[k * 64 + tid], acc);
    state[(size_t)b * 64 + tid] = fast_tanh(acc);
  }
}

// ---------------------------------------------------------------------------
extern "C" void kernel_launch(void* const* d_in, const int* in_sizes, int n_in,
                              void* d_out, int out_size, void* d_ws,
                              size_t ws_size, hipStream_t stream) {
  const float* x = (const float*)d_in[0];     // (64,512,64)
  const float* kmat = (const float*)d_in[1];  // (64,768)
  const float* wr = (const float*)d_in[2];    // (256,768)
  const float* bias = (const float*)d_in[3];  // (768,)
  const float* dw = (const float*)d_in[4];    // (256,64)
  const float* db = (const float*)d_in[5];    // (64,)

  float* out = (float*)d_out;                   // (64,512,256)
  float* state = out + (size_t)64 * 512 * 256;  // (64,64)
  _Float16* xp = (_Float16*)d_ws;               // 64*512*768 f16 = 48 MiB

  dim3 gg(32768 / 128, 768 / 128);
  xproj_gemm<<<gg, 256, 0, stream>>>(x, kmat, bias, xp);
  gru_scan_mfma<<<64, 512, 0, stream>>>(xp, wr, dw, db, out, state);
}